// Round 9
// baseline (133239.172 us; speedup 1.0000x reference)
//
#include <hip/hip_runtime.h>
#include <hip/hip_cooperative_groups.h>
#include <math.h>

namespace cg = cooperative_groups;

#define BB 64
#define TT 128
#define DBX 256
#define IND 264
#define HS 512
#define NH 4
#define MMM 128
#define AAA 2048
#define PPH 390
#define NCOLS 2072
#define KSPL 8
#define KCH  161
#define EPSF 1e-8f
#define SMEM_BYTES 41472   // (512+512+1024+32*260) floats = 10368*4

__device__ __forceinline__ float sigmf(float x){ return 1.0f/(1.0f+expf(-x)); }
__device__ __forceinline__ float softplusf(float x){ return (x > 20.0f) ? x : log1pf(expf(x)); }
__device__ __forceinline__ float wred64(float v){
  #pragma unroll
  for (int off=32; off>0; off>>=1) v += __shfl_xor(v, off);
  return v;
}

// ---------------- transpose x[b][t][i] -> xT[t*IND+i][b] (once) ----------------
__global__ __launch_bounds__(256) void k_tx(const float* __restrict__ x, float* __restrict__ xT){
  int b = blockIdx.x;
  for (int f = threadIdx.x; f < TT*IND; f += 256)
    xT[(size_t)f*BB + b] = x[(size_t)b*TT*IND + f];
}

// ================= persistent cooperative kernel =================
// 512 blocks x 256 threads; block = (b, s): b = bid>>3, s = bid&7.
// Thread owns column col = s*256+tid of mem[b][:][col] (128 regs) + wt[4].
__global__ __launch_bounds__(256, 2) void k_persist(
    const float* __restrict__ xT, const float* __restrict__ Wst, const float* __restrict__ bst,
    const float* __restrict__ Wout, const float* __restrict__ bout,
    const float* __restrict__ Wupd, const float* __restrict__ bupd,
    float* __restrict__ out,
    float* __restrict__ hT, float* __restrict__ readT, float* __restrict__ hpart,
    float* __restrict__ kvec_t, float* __restrict__ beta, float* __restrict__ gbuf,
    float* __restrict__ gam, float* __restrict__ shraw,
    float* __restrict__ erase, float* __restrict__ addb,
    float* __restrict__ wcsum, float* __restrict__ wpsum,
    float* __restrict__ haloL, float* __restrict__ haloR)
{
  cg::grid_group grid = cg::this_grid();
  extern __shared__ float sm[];
  const int bid = blockIdx.x, tid = threadIdx.x;
  const int b = bid >> 3, s = bid & 7;
  const int col = s*256 + tid;
  const int lane = tid & 63, wave = tid >> 6;

  float mem[128];
  #pragma unroll
  for (int m=0;m<128;++m) mem[m] = 0.01f;
  float wt[4];
  #pragma unroll
  for (int h=0;h<4;++h) wt[h] = (col==0)?1.0f:0.0f;
  float e_r[4], wp_r[4];

  // k1 decomposition: 512 blocks = 256 j-groups x 2 K-halves; waves: 2 j x 2 K-quarters
  const int jg = bid >> 1, kh = bid & 1;
  const int j1 = jg*2 + (wave & 1);
  const int kq = wave >> 1;
  const int k0 = kh*644 + kq*322;
  // k2 decomposition: blocks <488: 4 cols; >=488: 5 cols
  const int ncols = (bid < 488) ? 4 : 5;
  const int c0 = (bid < 488) ? bid*4 : 1952 + (bid-488)*5;

  for (int t=0; t<TT; ++t){
    // ======== P1: controller state GEMM partials ========
    {
      const float* xt  = xT + (size_t)t*IND*BB;
      const float* hTp = hT + ((t+1)&1)*HS*BB;
      const float* rTp = readT + (t&1)*HS*BB;
      const int kend = k0 + 322;
      float a0 = 0.0f;
      int ks_ = k0, ke_ = kend < IND ? kend : IND;
      #pragma unroll 4
      for (int k=ks_; k<ke_; ++k) a0 += xt[k*BB+lane]*Wst[(size_t)k*HS + j1];
      ks_ = k0 > IND ? k0 : IND; ke_ = kend < (IND+HS) ? kend : (IND+HS);
      if (t == 0){
        #pragma unroll 4
        for (int k=ks_; k<ke_; ++k) a0 += Wst[(size_t)k*HS + j1];          // h0 = 1
      } else {
        #pragma unroll 4
        for (int k=ks_; k<ke_; ++k) a0 += hTp[(k-IND)*BB+lane]*Wst[(size_t)k*HS + j1];
      }
      ks_ = k0 > (IND+HS) ? k0 : (IND+HS);
      if (t == 0){
        #pragma unroll 4
        for (int k=ks_; k<kend; ++k) a0 += 0.01f*Wst[(size_t)k*HS + j1];   // read0 = 0.01
      } else {
        #pragma unroll 4
        for (int k=ks_; k<kend; ++k) a0 += rTp[(k-IND-HS)*BB+lane]*Wst[(size_t)k*HS + j1];
      }
      hpart[(size_t)(kh*2+kq)*HS*BB + j1*BB + lane] = a0;
    }
    grid.sync();

    // ======== P2: h finalize + zero accumulators ========
    {
      int gid = bid*256 + tid;
      if (gid < HS*BB){
        float v = hpart[gid] + hpart[HS*BB+gid] + hpart[2*HS*BB+gid] + hpart[3*HS*BB+gid];
        hT[(t&1)*HS*BB + gid] = sigmf(v + bst[gid>>6]);
      } else if (gid < HS*BB + 256){
        wcsum[gid - HS*BB] = 0.0f;
      } else if (gid < HS*BB + 512){
        wpsum[gid - HS*BB - 256] = 0.0f;
      } else if (gid >= 2*HS*BB && gid < 3*HS*BB){
        readT[((t+1)&1)*HS*BB + (gid - 2*HS*BB)] = 0.0f;
      }
    }
    grid.sync();

    // ======== P3: out/upd GEMM + per-head transforms ========
    {
      const float* hc = hT + (t&1)*HS*BB;
      for (int ci = wave; ci < ncols; ci += 4){
        int c = c0 + ci;
        const float* wcol; int strd; float v;
        if (c < DBX){ wcol = Wout + c; strd = DBX; v = bout[c]; }
        else        { wcol = Wupd + (c-DBX); strd = NH*PPH; v = bupd[c-DBX]; }
        #pragma unroll 4
        for (int k=0; k<HS; ++k) v += hc[k*BB+lane]*wcol[(size_t)k*strd];
        if (c < DBX){
          out[((size_t)lane*TT + t)*DBX + c] = sigmf(v);
        } else {
          int u2 = c - DBX; int hh = u2/PPH; int p = u2 - hh*PPH;
          if (p < MMM)            kvec_t[lane*HS + p*NH + hh] = v;
          else if (p == MMM)      beta[lane*NH+hh] = softplusf(v);
          else if (p == MMM+1)    gbuf[lane*NH+hh] = sigmf(v);
          else if (p <  MMM+5)    shraw[(lane*NH+hh)*3 + (p-(MMM+2))] = v;
          else if (p == MMM+5)    gam[lane*NH+hh] = 1.0f + softplusf(v);
          else if (p <  2*MMM+6)  erase[lane*HS + hh*MMM + (p-(MMM+6))] = sigmf(v);
          else                    addb[lane*HS + hh*MMM + (p-(2*MMM+6))] = tanhf(v);
        }
      }
    }
    grid.sync();

    // ======== P4: content dots + e + wcsum + halo write ========
    {
      float* kl  = sm;        // [512]  layout [m*4+h]
      float* red = sm + 512;  // [256]
      float* pb  = sm + 768;  // [4]
      float* knl = sm + 772;  // [4]
      float* wsr = sm + 776;  // [16]
      kl[tid]     = kvec_t[b*HS + tid];
      kl[tid+256] = kvec_t[b*HS + 256 + tid];
      if (tid < 4) pb[tid] = beta[b*NH + tid];
      __syncthreads();
      red[tid] = kl[tid]*kl[tid] + kl[tid+256]*kl[tid+256];
      __syncthreads();
      for (int off=128; off>=4; off>>=1){
        if (tid < off) red[tid] += red[tid+off];
        __syncthreads();
      }
      if (tid < 4) knl[tid] = sqrtf(red[tid]);
      __syncthreads();
      const float4* kl4 = (const float4*)kl;
      float d0=0,d1=0,d2=0,d3=0,n2=0;
      #pragma unroll
      for (int m=0; m<128; ++m){
        float4 kv = kl4[m];
        float mv = mem[m];
        d0 += kv.x*mv; d1 += kv.y*mv; d2 += kv.z*mv; d3 += kv.w*mv;
        n2 += mv*mv;
      }
      float mn = sqrtf(n2);
      float dd[4] = {d0,d1,d2,d3};
      #pragma unroll
      for (int h=0; h<4; ++h){
        float sim = dd[h]/(knl[h]*mn + EPSF);
        e_r[h] = expf(pb[h]*sim);
      }
      #pragma unroll
      for (int h=0; h<4; ++h){
        float v = wred64(e_r[h]);
        if (lane == 0) wsr[wave*4+h] = v;
      }
      __syncthreads();
      if (tid < 4)
        atomicAdd(&wcsum[b*NH+tid], wsr[tid]+wsr[4+tid]+wsr[8+tid]+wsr[12+tid]);
      if (tid == 0){
        #pragma unroll
        for (int h=0;h<4;++h){ haloL[bid*8+h] = e_r[h]; haloL[bid*8+4+h] = wt[h]; }
      }
      if (tid == 255){
        #pragma unroll
        for (int h=0;h<4;++h){ haloR[bid*8+h] = e_r[h]; haloR[bid*8+4+h] = wt[h]; }
      }
    }
    grid.sync();

    // ======== P5: normalize + interpolate + shift + sharpen + wpsum ========
    {
      float (*ew)[9] = (float(*)[9])sm;    // [256][9]
      float* sh  = sm + 2304;  // [12]
      float* gg  = sm + 2316;
      float* gm  = sm + 2320;
      float* wci = sm + 2324;
      float* wsr = sm + 2328;  // [16]
      #pragma unroll
      for (int h=0;h<4;++h){ ew[tid][h] = e_r[h]; ew[tid][4+h] = wt[h]; }
      if (tid < 4){
        gg[tid] = gbuf[b*NH+tid];
        gm[tid] = gam[b*NH+tid];
        wci[tid] = 1.0f/wcsum[b*NH+tid];
        float s0 = shraw[(b*NH+tid)*3], s1 = shraw[(b*NH+tid)*3+1], s2 = shraw[(b*NH+tid)*3+2];
        float mx = fmaxf(s0, fmaxf(s1, s2));
        float e0 = expf(s0-mx), e1 = expf(s1-mx), e2 = expf(s2-mx);
        float inv = 1.0f/(e0+e1+e2);
        sh[tid*3] = e0*inv; sh[tid*3+1] = e1*inv; sh[tid*3+2] = e2*inv;
      }
      __syncthreads();
      float eL[4], wtL[4], eR[4], wtR[4];
      if (tid == 0){
        const float* hb = haloR + (b*8 + ((s+7)&7))*8;
        #pragma unroll
        for (int h=0;h<4;++h){ eL[h] = hb[h]; wtL[h] = hb[4+h]; }
      } else {
        #pragma unroll
        for (int h=0;h<4;++h){ eL[h] = ew[tid-1][h]; wtL[h] = ew[tid-1][4+h]; }
      }
      if (tid == 255){
        const float* hb = haloL + (b*8 + ((s+1)&7))*8;
        #pragma unroll
        for (int h=0;h<4;++h){ eR[h] = hb[h]; wtR[h] = hb[4+h]; }
      } else {
        #pragma unroll
        for (int h=0;h<4;++h){ eR[h] = ew[tid+1][h]; wtR[h] = ew[tid+1][4+h]; }
      }
      #pragma unroll
      for (int h=0; h<4; ++h){
        float g = gg[h], inv = wci[h];
        float wg0  = g*e_r[h]*inv + (1.0f-g)*wt[h];
        float wgm1 = g*eL[h]*inv  + (1.0f-g)*wtL[h];
        float wgp1 = g*eR[h]*inv  + (1.0f-g)*wtR[h];
        float ws = sh[h*3]*wgp1 + sh[h*3+1]*wg0 + sh[h*3+2]*wgm1;
        wp_r[h] = powf(ws + EPSF, gm[h]);
      }
      #pragma unroll
      for (int h=0; h<4; ++h){
        float v = wred64(wp_r[h]);
        if (lane == 0) wsr[wave*4+h] = v;
      }
      __syncthreads();
      if (tid < 4)
        atomicAdd(&wpsum[b*NH+tid], wsr[tid]+wsr[4+tid]+wsr[8+tid]+wsr[12+tid]);
    }
    grid.sync();

    // ======== P6: wt_new + mem update (regs) + read einsum (LDS transpose, 4 stages) ========
    {
      float* erT = sm;          // [512] [m*4+h]
      float* adT = sm + 512;    // [512]
      float* wl  = sm + 1024;   // [1024] [c*4+h]
      float* M   = sm + 2048;   // [32*260]
      #pragma unroll
      for (int h=0;h<4;++h) wt[h] = wp_r[h] / wpsum[b*NH+h];
      {
        int m0 = tid & 127, h0 = tid >> 7;   // h0 in {0,1}
        erT[m0*4 + h0]     = erase[b*HS + h0*MMM + m0];
        erT[m0*4 + 2 + h0] = erase[b*HS + (2+h0)*MMM + m0];
        adT[m0*4 + h0]     = addb [b*HS + h0*MMM + m0];
        adT[m0*4 + 2 + h0] = addb [b*HS + (2+h0)*MMM + m0];
      }
      #pragma unroll
      for (int h=0;h<4;++h) wl[tid*4+h] = wt[h];
      __syncthreads();
      const float4* e4 = (const float4*)erT;
      const float4* a4 = (const float4*)adT;
      #pragma unroll
      for (int m=0; m<128; ++m){
        float4 ev = e4[m], av = a4[m];
        float et = (1.0f - ev.x*wt[0])*(1.0f - ev.y*wt[1])
                 * (1.0f - ev.z*wt[2])*(1.0f - ev.w*wt[3]);
        float at = av.x*wt[0] + av.y*wt[1] + av.z*wt[2] + av.w*wt[3];
        mem[m] = mem[m]*et + at;
      }
      float* rT = readT + ((t+1)&1)*HS*BB;
      #pragma unroll
      for (int st=0; st<4; ++st){
        __syncthreads();
        #pragma unroll
        for (int ml=0; ml<32; ++ml) M[ml*260 + tid] = mem[st*32 + ml];
        __syncthreads();
        int mloc = tid >> 3;        // 0..31
        int h    = (tid >> 1) & 3;  // 0..3
        int half = tid & 1;         // 0..1
        float acc = 0.0f;
        #pragma unroll 8
        for (int j4=0; j4<32; ++j4){
          float4 mv = *(const float4*)&M[mloc*260 + half*128 + j4*4];
          acc += mv.x*wl[(half*128 + j4*4+0)*4+h] + mv.y*wl[(half*128 + j4*4+1)*4+h]
               + mv.z*wl[(half*128 + j4*4+2)*4+h] + mv.w*wl[(half*128 + j4*4+3)*4+h];
        }
        acc += __shfl_xor(acc, 1);
        if (half == 0)
          atomicAdd(&rT[(h*MMM + st*32 + mloc)*BB + b], acc);
      }
    }
    grid.sync();
  }
}

// ================= fallback: round-6 verified pipeline =================
__global__ void k_init(float* __restrict__ hT, float* __restrict__ readT,
                       float* __restrict__ wt, float* __restrict__ mem){
  int i = blockIdx.x*blockDim.x + threadIdx.x;
  int stride = gridDim.x*blockDim.x;
  for (int idx=i; idx<BB*MMM*AAA; idx+=stride) mem[idx]=0.01f;
  for (int idx=i; idx<HS*BB; idx+=stride){ hT[idx]=1.0f; readT[idx]=0.01f; }
  for (int idx=i; idx<BB*NH*AAA; idx+=stride) wt[idx] = ((idx & (AAA-1))==0)?1.0f:0.0f;
}

__global__ __launch_bounds__(256) void k1_state(
    const float* __restrict__ xT, const float* __restrict__ Wst,
    const float* __restrict__ hTp, const float* __restrict__ readTp,
    float* __restrict__ hpart, float* __restrict__ wcsum, float* __restrict__ wpsum, int t)
{
  int tid = threadIdx.x, wave = tid>>6, lane = tid&63;
  int ks = blockIdx.y;
  int j0 = blockIdx.x*16 + wave*4;
  if (blockIdx.x==0 && ks==0){
    wcsum[tid] = 0.0f;
    wpsum[tid] = 0.0f;
  }
  float a0=0,a1=0,a2=0,a3=0;
  int k0 = ks*KCH, kend = k0+KCH;

  #define K1STEP(AEXPR) { float aV=(AEXPR); \
      float4 wv = *(const float4*)(Wst + (size_t)k*HS + j0); \
      a0 += aV*wv.x; a1 += aV*wv.y; a2 += aV*wv.z; a3 += aV*wv.w; }

  {int s = k0, e = kend<IND?kend:IND;
   #pragma unroll 4
   for (int k=s;k<e;++k) K1STEP(xT[((size_t)t*IND + k)*BB + lane]); }
  {int s = k0>IND?k0:IND, e = kend<(IND+HS)?kend:(IND+HS);
   #pragma unroll 4
   for (int k=s;k<e;++k) K1STEP(hTp[(k-IND)*BB + lane]); }
  {int s = k0>(IND+HS)?k0:(IND+HS), e = kend;
   #pragma unroll 4
   for (int k=s;k<e;++k) K1STEP(readTp[(k-IND-HS)*BB + lane]); }
  #undef K1STEP

  float* hp = hpart + (size_t)ks*HS*BB + (size_t)j0*BB + lane;
  hp[0]    = a0;
  hp[BB]   = a1;
  hp[2*BB] = a2;
  hp[3*BB] = a3;
}

__global__ __launch_bounds__(512) void k2h(
    const float* __restrict__ hpart, const float* __restrict__ bst, float* __restrict__ hTn)
{
  int idx = blockIdx.x*512 + threadIdx.x;
  float v = 0.0f;
  #pragma unroll
  for (int ks=0; ks<KSPL; ++ks) v += hpart[(size_t)ks*HS*BB + idx];
  hTn[idx] = sigmf(v + bst[idx>>6]);
}

__global__ __launch_bounds__(256) void k2_outupd(
    const float* __restrict__ hTn,
    const float* __restrict__ Wout, const float* __restrict__ bout,
    const float* __restrict__ Wupd, const float* __restrict__ bupd,
    float* __restrict__ out,
    float* __restrict__ kvec_t, float* __restrict__ beta, float* __restrict__ gbuf,
    float* __restrict__ gam, float* __restrict__ shraw,
    float* __restrict__ erase, float* __restrict__ addb, int t)
{
  __shared__ float part[4][8][BB];
  int tid = threadIdx.x, ks = tid>>6, lane = tid&63;
  int c0 = blockIdx.x*8;
  bool isout = (c0 < DBX);
  size_t strd = isout ? (size_t)DBX : (size_t)(NH*PPH);
  const float* wbase = isout ? (Wout + c0) : (Wupd + (c0 - DBX));
  bool valid = (c0 < NCOLS);

  float acc[8] = {0,0,0,0,0,0,0,0};
  if (valid){
    int k0 = ks*128;
    #pragma unroll 4
    for (int k=k0; k<k0+128; ++k){
      float a = hTn[k*BB + lane];
      const float4* w4 = (const float4*)(wbase + (size_t)k*strd);
      float4 wa = w4[0], wb = w4[1];
      acc[0]+=a*wa.x; acc[1]+=a*wa.y; acc[2]+=a*wa.z; acc[3]+=a*wa.w;
      acc[4]+=a*wb.x; acc[5]+=a*wb.y; acc[6]+=a*wb.z; acc[7]+=a*wb.w;
    }
  }
  #pragma unroll
  for (int u=0; u<8; ++u) part[ks][u][lane] = acc[u];
  __syncthreads();
  if (!valid) return;

  for (int idx=tid; idx<8*BB; idx+=256){
    int u = idx>>6, b = idx&63;
    int c = c0+u;
    float v = part[0][u][b] + part[1][u][b] + part[2][u][b] + part[3][u][b];
    if (isout){
      out[((size_t)b*TT + t)*DBX + c] = sigmf(v + bout[c]);
    } else {
      int u2 = c - DBX;
      int hh = u2 / PPH;
      int p  = u2 - hh*PPH;
      v += bupd[u2];
      if (p < MMM)            kvec_t[b*HS + p*NH + hh] = v;
      else if (p == MMM)      beta[b*NH+hh] = softplusf(v);
      else if (p == MMM+1)    gbuf[b*NH+hh] = sigmf(v);
      else if (p <  MMM+5)    shraw[(b*NH+hh)*3 + (p-(MMM+2))] = v;
      else if (p == MMM+5)    gam[b*NH+hh] = 1.0f + softplusf(v);
      else if (p <  2*MMM+6)  erase[b*HS + hh*MMM + (p-(MMM+6))] = sigmf(v);
      else                    addb[b*HS + hh*MMM + (p-(2*MMM+6))] = tanhf(v);
    }
  }
}

__global__ __launch_bounds__(512) void k_dotsP(
    const float* __restrict__ mem, const float* __restrict__ kvec_t,
    float* __restrict__ dpart, float* __restrict__ n2part)
{
  int b = blockIdx.x, s = blockIdx.y, z = blockIdx.z, tid = threadIdx.x;
  __shared__ __align__(16) float klt[128];
  if (tid < 128) klt[tid] = kvec_t[b*HS + z*128 + tid];
  __syncthreads();
  int a = s*512 + tid;
  const float* mp = mem + (size_t)b*MMM*AAA + (size_t)(z*32)*AAA + a;
  const float4* k4 = (const float4*)klt;
  float a0=0,a1=0,a2=0,a3=0,n2=0;
  #pragma unroll 8
  for (int m=0; m<32; ++m){
    float mv = mp[(size_t)m*AAA];
    float4 kv = k4[m];
    a0 += kv.x*mv; a1 += kv.y*mv; a2 += kv.z*mv; a3 += kv.w*mv;
    n2 += mv*mv;
  }
  size_t base = ((size_t)(z*BB+b)*NH)*AAA + a;
  dpart[base]        = a0;
  dpart[base+AAA]    = a1;
  dpart[base+2*AAA]  = a2;
  dpart[base+3*AAA]  = a3;
  n2part[(size_t)(z*BB+b)*AAA + a] = n2;
}

__global__ __launch_bounds__(512) void k_dotsF(
    const float* __restrict__ dpart, const float* __restrict__ n2part,
    const float* __restrict__ kvec_t, const float* __restrict__ beta,
    float* __restrict__ ebuf, float* __restrict__ wcsum)
{
  int b = blockIdx.x, s = blockIdx.y, tid = threadIdx.x;
  __shared__ float red[HS];
  __shared__ float kn[NH];
  __shared__ float rsum[8*NH];
  float kv = kvec_t[b*HS + tid];
  red[tid] = kv*kv;
  __syncthreads();
  #pragma unroll
  for (int off=256; off>=4; off>>=1){
    if (tid < off) red[tid] += red[tid+off];
    __syncthreads();
  }
  if (tid < NH) kn[tid] = sqrtf(red[tid]);
  __syncthreads();

  int a = s*512 + tid;
  float d[NH] = {0,0,0,0};
  float n2 = 0.0f;
  #pragma unroll
  for (int z=0; z<4; ++z){
    size_t base = ((size_t)(z*BB+b)*NH)*AAA + a;
    d[0] += dpart[base];
    d[1] += dpart[base+AAA];
    d[2] += dpart[base+2*AAA];
    d[3] += dpart[base+3*AAA];
    n2   += n2part[(size_t)(z*BB+b)*AAA + a];
  }
  float mn = sqrtf(n2);
  int wid = tid >> 6, lane = tid & 63;
  #pragma unroll
  for (int hh=0; hh<NH; ++hh){
    float sim = d[hh]/(kn[hh]*mn + EPSF);
    float e = expf(beta[b*NH+hh]*sim);
    ebuf[((size_t)(b*NH+hh))*AAA + a] = e;
    float v = e;
    #pragma unroll
    for (int off=32; off>0; off>>=1) v += __shfl_xor(v, off);
    if (lane==0) rsum[wid*NH+hh] = v;
  }
  __syncthreads();
  if (tid < NH){
    float s2 = 0.0f;
    #pragma unroll
    for (int w=0; w<8; ++w) s2 += rsum[w*NH+tid];
    atomicAdd(&wcsum[b*NH+tid], s2);
  }
}

__global__ __launch_bounds__(512) void k_shift(
    const float* __restrict__ ebuf, const float* __restrict__ wcsum,
    const float* __restrict__ gbuf, const float* __restrict__ shraw,
    const float* __restrict__ gam, const float* __restrict__ wt,
    float* __restrict__ wpb, float* __restrict__ wpsum)
{
  int b = blockIdx.x, s = blockIdx.y, tid = threadIdx.x;
  int a = s*512 + tid;
  int am1 = (a + AAA - 1) & (AAA-1);
  int ap1 = (a + 1) & (AAA-1);
  __shared__ float sh[NH*3], gl[NH], gml[NH], winv[NH];
  __shared__ float rsum[8*NH];
  if (tid < NH){
    int hh = tid;
    float s0=shraw[(b*NH+hh)*3], s1=shraw[(b*NH+hh)*3+1], s2=shraw[(b*NH+hh)*3+2];
    float mx = fmaxf(s0, fmaxf(s1, s2));
    float e0=expf(s0-mx), e1=expf(s1-mx), e2=expf(s2-mx);
    float inv = 1.0f/(e0+e1+e2);
    sh[hh*3+0]=e0*inv; sh[hh*3+1]=e1*inv; sh[hh*3+2]=e2*inv;
    gl[hh]  = gbuf[b*NH+hh];
    gml[hh] = gam[b*NH+hh];
    winv[hh]= 1.0f/wcsum[b*NH+hh];
  }
  __syncthreads();
  int wid = tid >> 6, lane = tid & 63;
  #pragma unroll
  for (int hh=0; hh<NH; ++hh){
    const float* eb = ebuf + ((size_t)(b*NH+hh))*AAA;
    const float* wb = wt   + ((size_t)(b*NH+hh))*AAA;
    float inv = winv[hh], g = gl[hh];
    float s0 = sh[hh*3+0], s1 = sh[hh*3+1], s2 = sh[hh*3+2];
    float wgm1 = g*eb[am1]*inv + (1.0f-g)*wb[am1];
    float wg0  = g*eb[a]  *inv + (1.0f-g)*wb[a];
    float wgp1 = g*eb[ap1]*inv + (1.0f-g)*wb[ap1];
    float ws = s0*wgp1 + s1*wg0 + s2*wgm1;
    float wp = powf(ws + EPSF, gml[hh]);
    wpb[((size_t)(b*NH+hh))*AAA + a] = wp;
    float v = wp;
    #pragma unroll
    for (int off=32; off>0; off>>=1) v += __shfl_xor(v, off);
    if (lane==0) rsum[wid*NH+hh] = v;
  }
  __syncthreads();
  if (tid < NH){
    float s3 = 0.0f;
    #pragma unroll
    for (int w=0; w<8; ++w) s3 += rsum[w*NH+tid];
    atomicAdd(&wpsum[b*NH+tid], s3);
  }
}

__global__ __launch_bounds__(512) void k_updA(
    float* __restrict__ mem, const float* __restrict__ wpb, const float* __restrict__ wpsum,
    const float* __restrict__ erase, const float* __restrict__ addb,
    float* __restrict__ wt)
{
  int b = blockIdx.x, s = blockIdx.y, z = blockIdx.z, tid = threadIdx.x;
  int a = s*512 + tid;
  __shared__ __align__(16) float ert[128];
  __shared__ __align__(16) float adt[128];
  if (tid < 128){
    int m = tid >> 2, hh = tid & 3;
    ert[tid] = erase[b*HS + hh*MMM + z*32 + m];
    adt[tid] = addb [b*HS + hh*MMM + z*32 + m];
  }
  float wtn[NH];
  #pragma unroll
  for (int hh=0; hh<NH; ++hh){
    float w = wpb[((size_t)(b*NH+hh))*AAA + a] / wpsum[b*NH+hh];
    wtn[hh] = w;
    if (z == 0) wt[((size_t)(b*NH+hh))*AAA + a] = w;
  }
  __syncthreads();

  float* mp = mem + (size_t)b*MMM*AAA + (size_t)(z*32)*AAA + a;
  const float4* e4 = (const float4*)ert;
  const float4* a4 = (const float4*)adt;
  #pragma unroll 8
  for (int m=0; m<32; ++m){
    float mv = mp[(size_t)m*AAA];
    float4 ev = e4[m], av = a4[m];
    float et = (1.0f - ev.x*wtn[0]) * (1.0f - ev.y*wtn[1])
             * (1.0f - ev.z*wtn[2]) * (1.0f - ev.w*wtn[3]);
    float at = av.x*wtn[0] + av.y*wtn[1] + av.z*wtn[2] + av.w*wtn[3];
    mp[(size_t)m*AAA] = mv*et + at;
  }
}

__global__ __launch_bounds__(512) void k_updB(
    const float* __restrict__ mem, const float* __restrict__ wt,
    float* __restrict__ readTn)
{
  int b = blockIdx.x, my = blockIdx.y, tid = threadIdx.x;
  int wave = tid >> 6, lane = tid & 63;
  int m0 = my*8 + wave;
  int m1 = m0 + 64;
  const float* row0 = mem + (size_t)b*MMM*AAA + (size_t)m0*AAA;
  const float* row1 = mem + (size_t)b*MMM*AAA + (size_t)m1*AAA;
  const float* w0 = wt + ((size_t)(b*NH+0))*AAA;
  const float* w1 = wt + ((size_t)(b*NH+1))*AAA;
  const float* w2 = wt + ((size_t)(b*NH+2))*AAA;
  const float* w3 = wt + ((size_t)(b*NH+3))*AAA;
  float r00=0,r01=0,r02=0,r03=0, r10=0,r11=0,r12=0,r13=0;
  #pragma unroll 4
  for (int it=0; it<32; ++it){
    int a = it*64 + lane;
    float mv0 = row0[a], mv1 = row1[a];
    float wv0 = w0[a], wv1 = w1[a], wv2 = w2[a], wv3 = w3[a];
    r00 += mv0*wv0; r01 += mv0*wv1; r02 += mv0*wv2; r03 += mv0*wv3;
    r10 += mv1*wv0; r11 += mv1*wv1; r12 += mv1*wv2; r13 += mv1*wv3;
  }
  float rr[2][NH] = {{r00,r01,r02,r03},{r10,r11,r12,r13}};
  #pragma unroll
  for (int q=0; q<2; ++q){
    #pragma unroll
    for (int hh=0; hh<NH; ++hh){
      float v = rr[q][hh];
      #pragma unroll
      for (int off=32; off>0; off>>=1) v += __shfl_xor(v, off);
      rr[q][hh] = v;
    }
  }
  if (lane == 0){
    #pragma unroll
    for (int hh=0; hh<NH; ++hh){
      readTn[(size_t)(hh*MMM+m0)*BB + b] = rr[0][hh];
      readTn[(size_t)(hh*MMM+m1)*BB + b] = rr[1][hh];
    }
  }
}

extern "C" void kernel_launch(void* const* d_in, const int* in_sizes, int n_in,
                              void* d_out, int out_size, void* d_ws, size_t ws_size,
                              hipStream_t stream){
  const float* x    = (const float*)d_in[0];
  const float* Wst  = (const float*)d_in[1];
  const float* bst  = (const float*)d_in[2];
  const float* Wout = (const float*)d_in[3];
  const float* bout = (const float*)d_in[4];
  const float* Wupd = (const float*)d_in[5];
  const float* bupd = (const float*)d_in[6];
  float* out = (float*)d_out;

  float* p = (float*)d_ws;
  float* xT     = p; p += (size_t)TT*IND*BB;  // 8.65 MB
  float* hT     = p; p += 2*HS*BB;
  float* readT  = p; p += 2*HS*BB;
  float* hpart  = p; p += KSPL*HS*BB;         // 8 slices (persistent uses 4)
  float* kvec_t = p; p += BB*HS;
  float* beta   = p; p += BB*NH;
  float* gbuf   = p; p += BB*NH;
  float* gam    = p; p += BB*NH;
  float* shraw  = p; p += BB*NH*3;
  float* erase  = p; p += BB*HS;
  float* addb   = p; p += BB*HS;
  float* wcsum  = p; p += BB*NH;
  float* wpsum  = p; p += BB*NH;
  float* haloL  = p; p += 512*8;
  float* haloR  = p; p += 512*8;
  float* wt     = p; p += BB*NH*AAA;
  float* mem    = p; p += (size_t)BB*MMM*AAA;
  float* ebuf   = p; p += BB*NH*AAA;
  float* wpb    = p; p += 4*(size_t)BB*NH*AAA;
  float* n2part = p; p += 4*BB*AAA;
  float* dpart  = wpb;

  k_tx<<<BB, 256, 0, stream>>>(x, xT);

  void* args[] = { (void*)&xT, (void*)&Wst, (void*)&bst, (void*)&Wout, (void*)&bout,
                   (void*)&Wupd, (void*)&bupd, (void*)&out, (void*)&hT, (void*)&readT,
                   (void*)&hpart, (void*)&kvec_t, (void*)&beta, (void*)&gbuf, (void*)&gam,
                   (void*)&shraw, (void*)&erase, (void*)&addb, (void*)&wcsum, (void*)&wpsum,
                   (void*)&haloL, (void*)&haloR };
  hipError_t err = hipLaunchCooperativeKernel((void*)k_persist, dim3(512), dim3(256),
                                              args, SMEM_BYTES, stream);
  if (err != hipSuccess){
    // -------- fallback: round-6 verified multi-kernel pipeline --------
    k_init<<<2048, 256, 0, stream>>>(hT, readT, wt, mem);
    for (int t=0; t<TT; ++t){
      const float* hTp = hT    + (t&1)*HS*BB;
      float* hTn       = hT    + ((t+1)&1)*HS*BB;
      const float* rTp = readT + (t&1)*HS*BB;
      float* rTn       = readT + ((t+1)&1)*HS*BB;
      k1_state<<<dim3(32,KSPL), 256, 0, stream>>>(xT, Wst, hTp, rTp, hpart, wcsum, wpsum, t);
      k2h<<<64, 512, 0, stream>>>(hpart, bst, hTn);
      k2_outupd<<<dim3(259), 256, 0, stream>>>(hTn, Wout, bout, Wupd, bupd, out,
          kvec_t, beta, gbuf, gam, shraw, erase, addb, t);
      k_dotsP<<<dim3(BB,4,4), 512, 0, stream>>>(mem, kvec_t, dpart, n2part);
      k_dotsF<<<dim3(BB,4), 512, 0, stream>>>(dpart, n2part, kvec_t, beta, ebuf, wcsum);
      k_shift<<<dim3(BB,4), 512, 0, stream>>>(ebuf, wcsum, gbuf, shraw, gam, wt, wpb, wpsum);
      k_updA<<<dim3(BB,4,4), 512, 0, stream>>>(mem, wpb, wpsum, erase, addb, wt);
      k_updB<<<dim3(BB,8), 512, 0, stream>>>(mem, wt, rTn);
    }
  }
}

// Round 10
// 106514.038 us; speedup vs baseline: 1.2509x; 1.2509x over previous
//
#include <hip/hip_runtime.h>
#include <hip/hip_cooperative_groups.h>
#include <math.h>

namespace cg = cooperative_groups;

#define BB 64
#define TT 128
#define DBX 256
#define IND 264
#define HS 512
#define NH 4
#define MMM 128
#define AAA 2048
#define PPH 390
#define NCOLS 2072
#define KSPL 8
#define KCH  161
#define EPSF 1e-8f

__device__ __forceinline__ float sigmf(float x){ return 1.0f/(1.0f+expf(-x)); }
__device__ __forceinline__ float softplusf(float x){ return (x > 20.0f) ? x : log1pf(expf(x)); }
__device__ __forceinline__ float wred64(float v){
  #pragma unroll
  for (int off=32; off>0; off>>=1) v += __shfl_xor(v, off);
  return v;
}

// ---------------- transpose x[b][t][i] -> xT[t*IND+i][b] (once) ----------------
__global__ __launch_bounds__(256) void k_tx(const float* __restrict__ x, float* __restrict__ xT){
  int b = blockIdx.x;
  for (int f = threadIdx.x; f < TT*IND; f += 256)
    xT[(size_t)f*BB + b] = x[(size_t)b*TT*IND + f];
}

// ---------------- P1 helper: one (j, K-chunk) GEMV partial ----------------
__device__ __forceinline__ float p1_task(const float* __restrict__ xt, const float* __restrict__ Wst,
    const float* __restrict__ hTp, const float* __restrict__ rTp, int j, int k0, int lane, int t)
{
  const int kend = k0 + 322;
  float a0 = 0.0f;
  { int s_ = k0, e_ = kend < IND ? kend : IND;
    #pragma unroll 4
    for (int k=s_; k<e_; ++k) a0 += xt[k*BB+lane]*Wst[(size_t)k*HS + j]; }
  { int s_ = k0 > IND ? k0 : IND, e_ = kend < (IND+HS) ? kend : (IND+HS);
    if (t == 0){
      #pragma unroll 4
      for (int k=s_; k<e_; ++k) a0 += Wst[(size_t)k*HS + j];               // h0 = 1
    } else {
      #pragma unroll 4
      for (int k=s_; k<e_; ++k) a0 += hTp[(k-IND)*BB+lane]*Wst[(size_t)k*HS + j];
    } }
  { int s_ = k0 > (IND+HS) ? k0 : (IND+HS);
    if (t == 0){
      #pragma unroll 4
      for (int k=s_; k<kend; ++k) a0 += 0.01f*Wst[(size_t)k*HS + j];       // read0 = 0.01
    } else {
      #pragma unroll 4
      for (int k=s_; k<kend; ++k) a0 += rTp[(k-IND-HS)*BB+lane]*Wst[(size_t)k*HS + j];
    } }
  return a0;
}

// ================= persistent cooperative kernel =================
// 256 blocks x 256 threads, 1 block/CU, 1 wave/SIMD (launch_bounds(256,1) -> VGPR cap 512).
// block = (b, q): b = bid>>2, q = bid&3. Thread owns cols colA = q*512+tid, colB = colA+256:
// memA[128], memB[128] in registers (256 VGPRs).
__global__ __launch_bounds__(256, 1) void k_persist(
    const float* __restrict__ xT, const float* __restrict__ Wst, const float* __restrict__ bst,
    const float* __restrict__ Wout, const float* __restrict__ bout,
    const float* __restrict__ Wupd, const float* __restrict__ bupd,
    float* __restrict__ out,
    float* __restrict__ hT, float* __restrict__ readT, float* __restrict__ hpart,
    float* __restrict__ kvec_t, float* __restrict__ beta, float* __restrict__ gbuf,
    float* __restrict__ gam, float* __restrict__ shraw,
    float* __restrict__ erase, float* __restrict__ addb,
    float* __restrict__ wcsum, float* __restrict__ wpsum,
    float* __restrict__ haloL, float* __restrict__ haloR)
{
  cg::grid_group grid = cg::this_grid();
  __shared__ float sm[11584];   // 46.3 KB static
  const int bid = blockIdx.x, tid = threadIdx.x;
  const int b = bid >> 2, q = bid & 3;
  const int colA = q*512 + tid;            // colB = colA + 256
  const int lane = tid & 63, wave = tid >> 6;

  float memA[128], memB[128];
  #pragma unroll
  for (int m=0;m<128;++m){ memA[m] = 0.01f; memB[m] = 0.01f; }
  float wtA[4], wtB[4];
  #pragma unroll
  for (int h=0;h<4;++h){ wtA[h] = (colA==0)?1.0f:0.0f; wtB[h] = 0.0f; }
  float eA[4], eB[4], wpA[4], wpB[4];

  // P3 column mapping: blocks 0..231 -> 8 cols, 232..255 -> 9 cols
  const int ncols3 = (bid < 232) ? 8 : 9;
  const int c03 = (bid < 232) ? bid*8 : 1856 + (bid-232)*9;
  // P1 task mapping: 2048 tasks = 512 j x 4 kq over 1024 waves
  const int task0 = bid*4 + wave;

  for (int t=0; t<TT; ++t){
    // ======== P1: controller state GEMV partials (+zero wcsum/wpsum) ========
    {
      if (bid == 0) wcsum[tid] = 0.0f;
      if (bid == 1) wpsum[tid] = 0.0f;
      const float* xt  = xT + (size_t)t*IND*BB;
      const float* hTp = hT + ((t+1)&1)*HS*BB;
      const float* rTp = readT + (t&1)*HS*BB;
      {
        int j = task0 >> 2, kq = task0 & 3;
        float a = p1_task(xt, Wst, hTp, rTp, j, kq*322, lane, t);
        hpart[(size_t)kq*HS*BB + j*BB + lane] = a;
      }
      {
        int task1 = task0 + 1024;
        int j = task1 >> 2, kq = task1 & 3;
        float a = p1_task(xt, Wst, hTp, rTp, j, kq*322, lane, t);
        hpart[(size_t)kq*HS*BB + j*BB + lane] = a;
      }
    }
    grid.sync();

    // ======== P2: h finalize + zero next read accumulator ========
    {
      int gid = bid*256 + tid;    // 0..65535
      if (gid < HS*BB){
        float v = hpart[gid] + hpart[HS*BB+gid] + hpart[2*HS*BB+gid] + hpart[3*HS*BB+gid];
        hT[(t&1)*HS*BB + gid] = sigmf(v + bst[gid>>6]);
      } else {
        readT[((t+1)&1)*HS*BB + (gid - HS*BB)] = 0.0f;
      }
    }
    grid.sync();

    // ======== P3: out/upd GEMV + per-head transforms ========
    {
      const float* hc = hT + (t&1)*HS*BB;
      for (int ci = wave; ci < ncols3; ci += 4){
        int c = c03 + ci;
        const float* wcol; int strd; float v;
        if (c < DBX){ wcol = Wout + c; strd = DBX; v = bout[c]; }
        else        { wcol = Wupd + (c-DBX); strd = NH*PPH; v = bupd[c-DBX]; }
        #pragma unroll 4
        for (int k=0; k<HS; ++k) v += hc[k*BB+lane]*wcol[(size_t)k*strd];
        if (c < DBX){
          out[((size_t)lane*TT + t)*DBX + c] = sigmf(v);
        } else {
          int u2 = c - DBX; int hh = u2/PPH; int p = u2 - hh*PPH;
          if (p < MMM)            kvec_t[lane*HS + p*NH + hh] = v;
          else if (p == MMM)      beta[lane*NH+hh] = softplusf(v);
          else if (p == MMM+1)    gbuf[lane*NH+hh] = sigmf(v);
          else if (p <  MMM+5)    shraw[(lane*NH+hh)*3 + (p-(MMM+2))] = v;
          else if (p == MMM+5)    gam[lane*NH+hh] = 1.0f + softplusf(v);
          else if (p <  2*MMM+6)  erase[lane*HS + hh*MMM + (p-(MMM+6))] = sigmf(v);
          else                    addb[lane*HS + hh*MMM + (p-(2*MMM+6))] = tanhf(v);
        }
      }
    }
    grid.sync();

    // ======== P4: content dots + e + wcsum + halo ========
    {
      float* kl  = sm;        // [512] layout [m*4+h]
      float* red = sm + 512;  // [256]
      float* pb  = sm + 768;  // [4]
      float* knl = sm + 772;  // [4]
      float* wsr = sm + 776;  // [16]
      kl[tid]     = kvec_t[b*HS + tid];
      kl[tid+256] = kvec_t[b*HS + 256 + tid];
      if (tid < 4) pb[tid] = beta[b*NH + tid];
      __syncthreads();
      red[tid] = kl[tid]*kl[tid] + kl[tid+256]*kl[tid+256];
      __syncthreads();
      for (int off=128; off>=4; off>>=1){
        if (tid < off) red[tid] += red[tid+off];
        __syncthreads();
      }
      if (tid < 4) knl[tid] = sqrtf(red[tid]);
      __syncthreads();
      const float4* kl4 = (const float4*)kl;
      float dA0=0,dA1=0,dA2=0,dA3=0,nA=0;
      float dB0=0,dB1=0,dB2=0,dB3=0,nB=0;
      #pragma unroll
      for (int m=0; m<128; ++m){
        float4 kv = kl4[m];
        float va = memA[m], vb = memB[m];
        dA0 += kv.x*va; dA1 += kv.y*va; dA2 += kv.z*va; dA3 += kv.w*va; nA += va*va;
        dB0 += kv.x*vb; dB1 += kv.y*vb; dB2 += kv.z*vb; dB3 += kv.w*vb; nB += vb*vb;
      }
      float mnA = sqrtf(nA), mnB = sqrtf(nB);
      float dA[4] = {dA0,dA1,dA2,dA3}, dB[4] = {dB0,dB1,dB2,dB3};
      #pragma unroll
      for (int h=0; h<4; ++h){
        eA[h] = expf(pb[h] * (dA[h]/(knl[h]*mnA + EPSF)));
        eB[h] = expf(pb[h] * (dB[h]/(knl[h]*mnB + EPSF)));
      }
      #pragma unroll
      for (int h=0; h<4; ++h){
        float v = wred64(eA[h] + eB[h]);
        if (lane == 0) wsr[wave*4+h] = v;
      }
      __syncthreads();
      if (tid < 4)
        atomicAdd(&wcsum[b*NH+tid], wsr[tid]+wsr[4+tid]+wsr[8+tid]+wsr[12+tid]);
      if (tid == 0){
        #pragma unroll
        for (int h=0;h<4;++h){ haloL[bid*8+h] = eA[h]; haloL[bid*8+4+h] = wtA[h]; }
      }
      if (tid == 255){
        #pragma unroll
        for (int h=0;h<4;++h){ haloR[bid*8+h] = eB[h]; haloR[bid*8+4+h] = wtB[h]; }
      }
    }
    grid.sync();

    // ======== P5: normalize + interpolate + shift + sharpen + wpsum ========
    {
      float (*ew)[9] = (float(*)[9])sm;    // [512][9]
      float* sh  = sm + 4608;  // [12]
      float* gg  = sm + 4620;  // [4]
      float* gm  = sm + 4624;  // [4]
      float* wci = sm + 4628;  // [4]
      float* wsr = sm + 4632;  // [16]
      #pragma unroll
      for (int h=0;h<4;++h){
        ew[tid][h] = eA[h];     ew[tid][4+h] = wtA[h];
        ew[tid+256][h] = eB[h]; ew[tid+256][4+h] = wtB[h];
      }
      if (tid < 4){
        gg[tid] = gbuf[b*NH+tid];
        gm[tid] = gam[b*NH+tid];
        wci[tid] = 1.0f/wcsum[b*NH+tid];
        float s0 = shraw[(b*NH+tid)*3], s1 = shraw[(b*NH+tid)*3+1], s2 = shraw[(b*NH+tid)*3+2];
        float mx = fmaxf(s0, fmaxf(s1, s2));
        float e0 = expf(s0-mx), e1 = expf(s1-mx), e2 = expf(s2-mx);
        float inv = 1.0f/(e0+e1+e2);
        sh[tid*3] = e0*inv; sh[tid*3+1] = e1*inv; sh[tid*3+2] = e2*inv;
      }
      __syncthreads();
      float eLA[4], wLA[4], eRA[4], wRA[4];
      float eLB[4], wLB[4], eRB[4], wRB[4];
      if (tid == 0){
        const float* hb = haloR + (b*4 + ((q+3)&3))*8;
        #pragma unroll
        for (int h=0;h<4;++h){ eLA[h] = hb[h]; wLA[h] = hb[4+h]; }
      } else {
        #pragma unroll
        for (int h=0;h<4;++h){ eLA[h] = ew[tid-1][h]; wLA[h] = ew[tid-1][4+h]; }
      }
      #pragma unroll
      for (int h=0;h<4;++h){ eRA[h] = ew[tid+1][h]; wRA[h] = ew[tid+1][4+h]; }
      #pragma unroll
      for (int h=0;h<4;++h){ eLB[h] = ew[tid+255][h]; wLB[h] = ew[tid+255][4+h]; }
      if (tid == 255){
        const float* hb = haloL + (b*4 + ((q+1)&3))*8;
        #pragma unroll
        for (int h=0;h<4;++h){ eRB[h] = hb[h]; wRB[h] = hb[4+h]; }
      } else {
        #pragma unroll
        for (int h=0;h<4;++h){ eRB[h] = ew[tid+257][h]; wRB[h] = ew[tid+257][4+h]; }
      }
      #pragma unroll
      for (int h=0; h<4; ++h){
        float g = gg[h], inv = wci[h];
        float s0 = sh[h*3], s1 = sh[h*3+1], s2 = sh[h*3+2], gmh = gm[h];
        float wg0A = g*eA[h]*inv  + (1.0f-g)*wtA[h];
        float wgLA = g*eLA[h]*inv + (1.0f-g)*wLA[h];
        float wgRA = g*eRA[h]*inv + (1.0f-g)*wRA[h];
        wpA[h] = powf(s0*wgRA + s1*wg0A + s2*wgLA + EPSF, gmh);
        float wg0B = g*eB[h]*inv  + (1.0f-g)*wtB[h];
        float wgLB = g*eLB[h]*inv + (1.0f-g)*wLB[h];
        float wgRB = g*eRB[h]*inv + (1.0f-g)*wRB[h];
        wpB[h] = powf(s0*wgRB + s1*wg0B + s2*wgLB + EPSF, gmh);
      }
      #pragma unroll
      for (int h=0; h<4; ++h){
        float v = wred64(wpA[h] + wpB[h]);
        if (lane == 0) wsr[wave*4+h] = v;
      }
      __syncthreads();
      if (tid < 4)
        atomicAdd(&wpsum[b*NH+tid], wsr[tid]+wsr[4+tid]+wsr[8+tid]+wsr[12+tid]);
    }
    grid.sync();

    // ======== P6: wt_new + mem update (regs) + read einsum (padded LDS transpose) ========
    {
      float* erT = sm;          // [512] [m*4+h]
      float* adT = sm + 512;    // [512]
      float* wlT = sm + 1024;   // [4][528] padded per-col weights
      float* M   = sm + 3136;   // [16][528]
      #pragma unroll
      for (int h=0;h<4;++h){
        float ws = wpsum[b*NH+h];
        wtA[h] = wpA[h] / ws;
        wtB[h] = wpB[h] / ws;
      }
      {
        int m0 = tid & 127, h0 = tid >> 7;   // h0 in {0,1}
        erT[m0*4 + h0]     = erase[b*HS + h0*MMM + m0];
        erT[m0*4 + 2 + h0] = erase[b*HS + (2+h0)*MMM + m0];
        adT[m0*4 + h0]     = addb [b*HS + h0*MMM + m0];
        adT[m0*4 + 2 + h0] = addb [b*HS + (2+h0)*MMM + m0];
      }
      {
        int pa = tid + ((tid>>7)<<2);              // padded col index for colA-local (tid)
        int pb2 = (tid+256) + (((tid+256)>>7)<<2); // for colB-local (tid+256)
        #pragma unroll
        for (int h=0;h<4;++h){
          wlT[h*528 + pa]  = wtA[h];
          wlT[h*528 + pb2] = wtB[h];
        }
      }
      __syncthreads();
      const float4* e4 = (const float4*)erT;
      const float4* a4 = (const float4*)adT;
      #pragma unroll
      for (int m=0; m<128; ++m){
        float4 ev = e4[m], av = a4[m];
        float etA = (1.0f - ev.x*wtA[0])*(1.0f - ev.y*wtA[1])
                  * (1.0f - ev.z*wtA[2])*(1.0f - ev.w*wtA[3]);
        float atA = av.x*wtA[0] + av.y*wtA[1] + av.z*wtA[2] + av.w*wtA[3];
        memA[m] = memA[m]*etA + atA;
        float etB = (1.0f - ev.x*wtB[0])*(1.0f - ev.y*wtB[1])
                  * (1.0f - ev.z*wtB[2])*(1.0f - ev.w*wtB[3]);
        float atB = av.x*wtB[0] + av.y*wtB[1] + av.z*wtB[2] + av.w*wtB[3];
        memB[m] = memB[m]*etB + atB;
      }
      float* rT = readT + ((t+1)&1)*HS*BB;
      const int pa = tid + ((tid>>7)<<2);
      const int pb2 = (tid+256) + (((tid+256)>>7)<<2);
      const int task = tid >> 2, qq = tid & 3;
      const int row = task >> 2, hh = task & 3;
      #pragma unroll
      for (int st=0; st<8; ++st){
        __syncthreads();
        #pragma unroll
        for (int r=0; r<16; ++r){
          M[r*528 + pa]  = memA[st*16 + r];
          M[r*528 + pb2] = memB[st*16 + r];
        }
        __syncthreads();
        float acc = 0.0f;
        #pragma unroll
        for (int j4=0; j4<32; ++j4){
          float4 mv = *(const float4*)&M[row*528 + qq*132 + j4*4];
          float4 wv = *(const float4*)&wlT[hh*528 + qq*132 + j4*4];
          acc += mv.x*wv.x + mv.y*wv.y + mv.z*wv.z + mv.w*wv.w;
        }
        acc += __shfl_xor(acc, 1);
        acc += __shfl_xor(acc, 2);
        if (qq == 0)
          atomicAdd(&rT[(hh*MMM + st*16 + row)*BB + b], acc);
      }
    }
    grid.sync();
  }
}

// ================= fallback: round-6 verified pipeline =================
__global__ void k_init(float* __restrict__ hT, float* __restrict__ readT,
                       float* __restrict__ wt, float* __restrict__ mem){
  int i = blockIdx.x*blockDim.x + threadIdx.x;
  int stride = gridDim.x*blockDim.x;
  for (int idx=i; idx<BB*MMM*AAA; idx+=stride) mem[idx]=0.01f;
  for (int idx=i; idx<HS*BB; idx+=stride){ hT[idx]=1.0f; readT[idx]=0.01f; }
  for (int idx=i; idx<BB*NH*AAA; idx+=stride) wt[idx] = ((idx & (AAA-1))==0)?1.0f:0.0f;
}

__global__ __launch_bounds__(256) void k1_state(
    const float* __restrict__ xT, const float* __restrict__ Wst,
    const float* __restrict__ hTp, const float* __restrict__ readTp,
    float* __restrict__ hpart, float* __restrict__ wcsum, float* __restrict__ wpsum, int t)
{
  int tid = threadIdx.x, wave = tid>>6, lane = tid&63;
  int ks = blockIdx.y;
  int j0 = blockIdx.x*16 + wave*4;
  if (blockIdx.x==0 && ks==0){
    wcsum[tid] = 0.0f;
    wpsum[tid] = 0.0f;
  }
  float a0=0,a1=0,a2=0,a3=0;
  int k0 = ks*KCH, kend = k0+KCH;

  #define K1STEP(AEXPR) { float aV=(AEXPR); \
      float4 wv = *(const float4*)(Wst + (size_t)k*HS + j0); \
      a0 += aV*wv.x; a1 += aV*wv.y; a2 += aV*wv.z; a3 += aV*wv.w; }

  {int s = k0, e = kend<IND?kend:IND;
   #pragma unroll 4
   for (int k=s;k<e;++k) K1STEP(xT[((size_t)t*IND + k)*BB + lane]); }
  {int s = k0>IND?k0:IND, e = kend<(IND+HS)?kend:(IND+HS);
   #pragma unroll 4
   for (int k=s;k<e;++k) K1STEP(hTp[(k-IND)*BB + lane]); }
  {int s = k0>(IND+HS)?k0:(IND+HS), e = kend;
   #pragma unroll 4
   for (int k=s;k<e;++k) K1STEP(readTp[(k-IND-HS)*BB + lane]); }
  #undef K1STEP

  float* hp = hpart + (size_t)ks*HS*BB + (size_t)j0*BB + lane;
  hp[0]    = a0;
  hp[BB]   = a1;
  hp[2*BB] = a2;
  hp[3*BB] = a3;
}

__global__ __launch_bounds__(512) void k2h(
    const float* __restrict__ hpart, const float* __restrict__ bst, float* __restrict__ hTn)
{
  int idx = blockIdx.x*512 + threadIdx.x;
  float v = 0.0f;
  #pragma unroll
  for (int ks=0; ks<KSPL; ++ks) v += hpart[(size_t)ks*HS*BB + idx];
  hTn[idx] = sigmf(v + bst[idx>>6]);
}

__global__ __launch_bounds__(256) void k2_outupd(
    const float* __restrict__ hTn,
    const float* __restrict__ Wout, const float* __restrict__ bout,
    const float* __restrict__ Wupd, const float* __restrict__ bupd,
    float* __restrict__ out,
    float* __restrict__ kvec_t, float* __restrict__ beta, float* __restrict__ gbuf,
    float* __restrict__ gam, float* __restrict__ shraw,
    float* __restrict__ erase, float* __restrict__ addb, int t)
{
  __shared__ float part[4][8][BB];
  int tid = threadIdx.x, ks = tid>>6, lane = tid&63;
  int c0 = blockIdx.x*8;
  bool isout = (c0 < DBX);
  size_t strd = isout ? (size_t)DBX : (size_t)(NH*PPH);
  const float* wbase = isout ? (Wout + c0) : (Wupd + (c0 - DBX));
  bool valid = (c0 < NCOLS);

  float acc[8] = {0,0,0,0,0,0,0,0};
  if (valid){
    int k0 = ks*128;
    #pragma unroll 4
    for (int k=k0; k<k0+128; ++k){
      float a = hTn[k*BB + lane];
      const float4* w4 = (const float4*)(wbase + (size_t)k*strd);
      float4 wa = w4[0], wb = w4[1];
      acc[0]+=a*wa.x; acc[1]+=a*wa.y; acc[2]+=a*wa.z; acc[3]+=a*wa.w;
      acc[4]+=a*wb.x; acc[5]+=a*wb.y; acc[6]+=a*wb.z; acc[7]+=a*wb.w;
    }
  }
  #pragma unroll
  for (int u=0; u<8; ++u) part[ks][u][lane] = acc[u];
  __syncthreads();
  if (!valid) return;

  for (int idx=tid; idx<8*BB; idx+=256){
    int u = idx>>6, b = idx&63;
    int c = c0+u;
    float v = part[0][u][b] + part[1][u][b] + part[2][u][b] + part[3][u][b];
    if (isout){
      out[((size_t)b*TT + t)*DBX + c] = sigmf(v + bout[c]);
    } else {
      int u2 = c - DBX;
      int hh = u2 / PPH;
      int p  = u2 - hh*PPH;
      v += bupd[u2];
      if (p < MMM)            kvec_t[b*HS + p*NH + hh] = v;
      else if (p == MMM)      beta[b*NH+hh] = softplusf(v);
      else if (p == MMM+1)    gbuf[b*NH+hh] = sigmf(v);
      else if (p <  MMM+5)    shraw[(b*NH+hh)*3 + (p-(MMM+2))] = v;
      else if (p == MMM+5)    gam[b*NH+hh] = 1.0f + softplusf(v);
      else if (p <  2*MMM+6)  erase[b*HS + hh*MMM + (p-(MMM+6))] = sigmf(v);
      else                    addb[b*HS + hh*MMM + (p-(2*MMM+6))] = tanhf(v);
    }
  }
}

__global__ __launch_bounds__(512) void k_dotsP(
    const float* __restrict__ mem, const float* __restrict__ kvec_t,
    float* __restrict__ dpart, float* __restrict__ n2part)
{
  int b = blockIdx.x, s = blockIdx.y, z = blockIdx.z, tid = threadIdx.x;
  __shared__ __align__(16) float klt[128];
  if (tid < 128) klt[tid] = kvec_t[b*HS + z*128 + tid];
  __syncthreads();
  int a = s*512 + tid;
  const float* mp = mem + (size_t)b*MMM*AAA + (size_t)(z*32)*AAA + a;
  const float4* k4 = (const float4*)klt;
  float a0=0,a1=0,a2=0,a3=0,n2=0;
  #pragma unroll 8
  for (int m=0; m<32; ++m){
    float mv = mp[(size_t)m*AAA];
    float4 kv = k4[m];
    a0 += kv.x*mv; a1 += kv.y*mv; a2 += kv.z*mv; a3 += kv.w*mv;
    n2 += mv*mv;
  }
  size_t base = ((size_t)(z*BB+b)*NH)*AAA + a;
  dpart[base]        = a0;
  dpart[base+AAA]    = a1;
  dpart[base+2*AAA]  = a2;
  dpart[base+3*AAA]  = a3;
  n2part[(size_t)(z*BB+b)*AAA + a] = n2;
}

__global__ __launch_bounds__(512) void k_dotsF(
    const float* __restrict__ dpart, const float* __restrict__ n2part,
    const float* __restrict__ kvec_t, const float* __restrict__ beta,
    float* __restrict__ ebuf, float* __restrict__ wcsum)
{
  int b = blockIdx.x, s = blockIdx.y, tid = threadIdx.x;
  __shared__ float red[HS];
  __shared__ float kn[NH];
  __shared__ float rsum[8*NH];
  float kv = kvec_t[b*HS + tid];
  red[tid] = kv*kv;
  __syncthreads();
  #pragma unroll
  for (int off=256; off>=4; off>>=1){
    if (tid < off) red[tid] += red[tid+off];
    __syncthreads();
  }
  if (tid < NH) kn[tid] = sqrtf(red[tid]);
  __syncthreads();

  int a = s*512 + tid;
  float d[NH] = {0,0,0,0};
  float n2 = 0.0f;
  #pragma unroll
  for (int z=0; z<4; ++z){
    size_t base = ((size_t)(z*BB+b)*NH)*AAA + a;
    d[0] += dpart[base];
    d[1] += dpart[base+AAA];
    d[2] += dpart[base+2*AAA];
    d[3] += dpart[base+3*AAA];
    n2   += n2part[(size_t)(z*BB+b)*AAA + a];
  }
  float mn = sqrtf(n2);
  int wid = tid >> 6, lane = tid & 63;
  #pragma unroll
  for (int hh=0; hh<NH; ++hh){
    float sim = d[hh]/(kn[hh]*mn + EPSF);
    float e = expf(beta[b*NH+hh]*sim);
    ebuf[((size_t)(b*NH+hh))*AAA + a] = e;
    float v = e;
    #pragma unroll
    for (int off=32; off>0; off>>=1) v += __shfl_xor(v, off);
    if (lane==0) rsum[wid*NH+hh] = v;
  }
  __syncthreads();
  if (tid < NH){
    float s2 = 0.0f;
    #pragma unroll
    for (int w=0; w<8; ++w) s2 += rsum[w*NH+tid];
    atomicAdd(&wcsum[b*NH+tid], s2);
  }
}

__global__ __launch_bounds__(512) void k_shift(
    const float* __restrict__ ebuf, const float* __restrict__ wcsum,
    const float* __restrict__ gbuf, const float* __restrict__ shraw,
    const float* __restrict__ gam, const float* __restrict__ wt,
    float* __restrict__ wpb, float* __restrict__ wpsum)
{
  int b = blockIdx.x, s = blockIdx.y, tid = threadIdx.x;
  int a = s*512 + tid;
  int am1 = (a + AAA - 1) & (AAA-1);
  int ap1 = (a + 1) & (AAA-1);
  __shared__ float sh[NH*3], gl[NH], gml[NH], winv[NH];
  __shared__ float rsum[8*NH];
  if (tid < NH){
    int hh = tid;
    float s0=shraw[(b*NH+hh)*3], s1=shraw[(b*NH+hh)*3+1], s2=shraw[(b*NH+hh)*3+2];
    float mx = fmaxf(s0, fmaxf(s1, s2));
    float e0=expf(s0-mx), e1=expf(s1-mx), e2=expf(s2-mx);
    float inv = 1.0f/(e0+e1+e2);
    sh[hh*3+0]=e0*inv; sh[hh*3+1]=e1*inv; sh[hh*3+2]=e2*inv;
    gl[hh]  = gbuf[b*NH+hh];
    gml[hh] = gam[b*NH+hh];
    winv[hh]= 1.0f/wcsum[b*NH+hh];
  }
  __syncthreads();
  int wid = tid >> 6, lane = tid & 63;
  #pragma unroll
  for (int hh=0; hh<NH; ++hh){
    const float* eb = ebuf + ((size_t)(b*NH+hh))*AAA;
    const float* wb = wt   + ((size_t)(b*NH+hh))*AAA;
    float inv = winv[hh], g = gl[hh];
    float s0 = sh[hh*3+0], s1 = sh[hh*3+1], s2 = sh[hh*3+2];
    float wgm1 = g*eb[am1]*inv + (1.0f-g)*wb[am1];
    float wg0  = g*eb[a]  *inv + (1.0f-g)*wb[a];
    float wgp1 = g*eb[ap1]*inv + (1.0f-g)*wb[ap1];
    float ws = s0*wgp1 + s1*wg0 + s2*wgm1;
    float wp = powf(ws + EPSF, gml[hh]);
    wpb[((size_t)(b*NH+hh))*AAA + a] = wp;
    float v = wp;
    #pragma unroll
    for (int off=32; off>0; off>>=1) v += __shfl_xor(v, off);
    if (lane==0) rsum[wid*NH+hh] = v;
  }
  __syncthreads();
  if (tid < NH){
    float s3 = 0.0f;
    #pragma unroll
    for (int w=0; w<8; ++w) s3 += rsum[w*NH+tid];
    atomicAdd(&wpsum[b*NH+tid], s3);
  }
}

__global__ __launch_bounds__(512) void k_updA(
    float* __restrict__ mem, const float* __restrict__ wpb, const float* __restrict__ wpsum,
    const float* __restrict__ erase, const float* __restrict__ addb,
    float* __restrict__ wt)
{
  int b = blockIdx.x, s = blockIdx.y, z = blockIdx.z, tid = threadIdx.x;
  int a = s*512 + tid;
  __shared__ __align__(16) float ert[128];
  __shared__ __align__(16) float adt[128];
  if (tid < 128){
    int m = tid >> 2, hh = tid & 3;
    ert[tid] = erase[b*HS + hh*MMM + z*32 + m];
    adt[tid] = addb [b*HS + hh*MMM + z*32 + m];
  }
  float wtn[NH];
  #pragma unroll
  for (int hh=0; hh<NH; ++hh){
    float w = wpb[((size_t)(b*NH+hh))*AAA + a] / wpsum[b*NH+hh];
    wtn[hh] = w;
    if (z == 0) wt[((size_t)(b*NH+hh))*AAA + a] = w;
  }
  __syncthreads();

  float* mp = mem + (size_t)b*MMM*AAA + (size_t)(z*32)*AAA + a;
  const float4* e4 = (const float4*)ert;
  const float4* a4 = (const float4*)adt;
  #pragma unroll 8
  for (int m=0; m<32; ++m){
    float mv = mp[(size_t)m*AAA];
    float4 ev = e4[m], av = a4[m];
    float et = (1.0f - ev.x*wtn[0]) * (1.0f - ev.y*wtn[1])
             * (1.0f - ev.z*wtn[2]) * (1.0f - ev.w*wtn[3]);
    float at = av.x*wtn[0] + av.y*wtn[1] + av.z*wtn[2] + av.w*wtn[3];
    mp[(size_t)m*AAA] = mv*et + at;
  }
}

__global__ __launch_bounds__(512) void k_updB(
    const float* __restrict__ mem, const float* __restrict__ wt,
    float* __restrict__ readTn)
{
  int b = blockIdx.x, my = blockIdx.y, tid = threadIdx.x;
  int wave = tid >> 6, lane = tid & 63;
  int m0 = my*8 + wave;
  int m1 = m0 + 64;
  const float* row0 = mem + (size_t)b*MMM*AAA + (size_t)m0*AAA;
  const float* row1 = mem + (size_t)b*MMM*AAA + (size_t)m1*AAA;
  const float* w0 = wt + ((size_t)(b*NH+0))*AAA;
  const float* w1 = wt + ((size_t)(b*NH+1))*AAA;
  const float* w2 = wt + ((size_t)(b*NH+2))*AAA;
  const float* w3 = wt + ((size_t)(b*NH+3))*AAA;
  float r00=0,r01=0,r02=0,r03=0, r10=0,r11=0,r12=0,r13=0;
  #pragma unroll 4
  for (int it=0; it<32; ++it){
    int a = it*64 + lane;
    float mv0 = row0[a], mv1 = row1[a];
    float wv0 = w0[a], wv1 = w1[a], wv2 = w2[a], wv3 = w3[a];
    r00 += mv0*wv0; r01 += mv0*wv1; r02 += mv0*wv2; r03 += mv0*wv3;
    r10 += mv1*wv0; r11 += mv1*wv1; r12 += mv1*wv2; r13 += mv1*wv3;
  }
  float rr[2][NH] = {{r00,r01,r02,r03},{r10,r11,r12,r13}};
  #pragma unroll
  for (int q=0; q<2; ++q){
    #pragma unroll
    for (int hh=0; hh<NH; ++hh){
      float v = rr[q][hh];
      #pragma unroll
      for (int off=32; off>0; off>>=1) v += __shfl_xor(v, off);
      rr[q][hh] = v;
    }
  }
  if (lane == 0){
    #pragma unroll
    for (int hh=0; hh<NH; ++hh){
      readTn[(size_t)(hh*MMM+m0)*BB + b] = rr[0][hh];
      readTn[(size_t)(hh*MMM+m1)*BB + b] = rr[1][hh];
    }
  }
}

extern "C" void kernel_launch(void* const* d_in, const int* in_sizes, int n_in,
                              void* d_out, int out_size, void* d_ws, size_t ws_size,
                              hipStream_t stream){
  const float* x    = (const float*)d_in[0];
  const float* Wst  = (const float*)d_in[1];
  const float* bst  = (const float*)d_in[2];
  const float* Wout = (const float*)d_in[3];
  const float* bout = (const float*)d_in[4];
  const float* Wupd = (const float*)d_in[5];
  const float* bupd = (const float*)d_in[6];
  float* out = (float*)d_out;

  float* p = (float*)d_ws;
  float* xT     = p; p += (size_t)TT*IND*BB;  // 8.65 MB
  float* hT     = p; p += 2*HS*BB;
  float* readT  = p; p += 2*HS*BB;
  float* hpart  = p; p += KSPL*HS*BB;
  float* kvec_t = p; p += BB*HS;
  float* beta   = p; p += BB*NH;
  float* gbuf   = p; p += BB*NH;
  float* gam    = p; p += BB*NH;
  float* shraw  = p; p += BB*NH*3;
  float* erase  = p; p += BB*HS;
  float* addb   = p; p += BB*HS;
  float* wcsum  = p; p += BB*NH;
  float* wpsum  = p; p += BB*NH;
  float* haloL  = p; p += 1024*8;
  float* haloR  = p; p += 1024*8;
  float* wt     = p; p += BB*NH*AAA;
  float* mem    = p; p += (size_t)BB*MMM*AAA;
  float* ebuf   = p; p += BB*NH*AAA;
  float* wpb    = p; p += 4*(size_t)BB*NH*AAA;
  float* n2part = p; p += 4*BB*AAA;
  float* dpart  = wpb;

  k_tx<<<BB, 256, 0, stream>>>(x, xT);

  void* args[] = { (void*)&xT, (void*)&Wst, (void*)&bst, (void*)&Wout, (void*)&bout,
                   (void*)&Wupd, (void*)&bupd, (void*)&out, (void*)&hT, (void*)&readT,
                   (void*)&hpart, (void*)&kvec_t, (void*)&beta, (void*)&gbuf, (void*)&gam,
                   (void*)&shraw, (void*)&erase, (void*)&addb, (void*)&wcsum, (void*)&wpsum,
                   (void*)&haloL, (void*)&haloR };
  hipError_t err = hipLaunchCooperativeKernel((void*)k_persist, dim3(256), dim3(256),
                                              args, 0, stream);
  if (err != hipSuccess){
    // -------- fallback: round-6 verified multi-kernel pipeline --------
    k_init<<<2048, 256, 0, stream>>>(hT, readT, wt, mem);
    for (int t=0; t<TT; ++t){
      const float* hTp = hT    + (t&1)*HS*BB;
      float* hTn       = hT    + ((t+1)&1)*HS*BB;
      const float* rTp = readT + (t&1)*HS*BB;
      float* rTn       = readT + ((t+1)&1)*HS*BB;
      k1_state<<<dim3(32,KSPL), 256, 0, stream>>>(xT, Wst, hTp, rTp, hpart, wcsum, wpsum, t);
      k2h<<<64, 512, 0, stream>>>(hpart, bst, hTn);
      k2_outupd<<<dim3(259), 256, 0, stream>>>(hTn, Wout, bout, Wupd, bupd, out,
          kvec_t, beta, gbuf, gam, shraw, erase, addb, t);
      k_dotsP<<<dim3(BB,4,4), 512, 0, stream>>>(mem, kvec_t, dpart, n2part);
      k_dotsF<<<dim3(BB,4), 512, 0, stream>>>(dpart, n2part, kvec_t, beta, ebuf, wcsum);
      k_shift<<<dim3(BB,4), 512, 0, stream>>>(ebuf, wcsum, gbuf, shraw, gam, wt, wpb, wpsum);
      k_updA<<<dim3(BB,4,4), 512, 0, stream>>>(mem, wpb, wpsum, erase, addb, wt);
      k_updB<<<dim3(BB,8), 512, 0, stream>>>(mem, wt, rTn);
    }
  }
}